// Round 3
// baseline (446.956 us; speedup 1.0000x reference)
//
#include <hip/hip_runtime.h>
#include <math.h>

#define NTOT 6148
#define NB 64
#define DM 512
#define SCALE_F 0.17677669529663687f

// ---------------- starts from batch array ----------------
__global__ __launch_bounds__(256) void k_starts(const int* __restrict__ batch,
                                                int* __restrict__ starts) {
  int i = blockIdx.x * 256 + threadIdx.x;
  if (i >= NTOT) return;
  int b = batch[i];
  if (i == 0) starts[b] = 0;
  else if (batch[i - 1] != b) starts[b] = i;
  if (i == NTOT - 1) starts[NB] = NTOT;
}

// ---------------- C[M][N] = A[M][K=512] @ W[N][K]^T + bias ----------------
// BM=BN=128, BK=8, 256 threads, 8x8 per thread. N = gridDim.y*128 (=512).
__global__ __launch_bounds__(256) void k_gemm(const float* __restrict__ A, int lda,
                                              const float* __restrict__ W,
                                              const float* __restrict__ bias,
                                              float* __restrict__ C, int ldc, int M) {
  __shared__ float As[8][128];
  __shared__ float Bs[8][128];
  const int tid = threadIdx.x;
  const int tx = tid & 15, ty = tid >> 4;
  const int m0 = blockIdx.x * 128, n0 = blockIdx.y * 128;
  const int r = tid >> 1, kq = (tid & 1) * 4;
  float acc[8][8];
#pragma unroll
  for (int i = 0; i < 8; i++)
#pragma unroll
    for (int j = 0; j < 8; j++) acc[i][j] = 0.f;

  for (int k0 = 0; k0 < DM; k0 += 8) {
    float4 av = make_float4(0.f, 0.f, 0.f, 0.f);
    const int gm = m0 + r;
    if (gm < M) av = *(const float4*)&A[(long)gm * lda + k0 + kq];
    const float4 bv = *(const float4*)&W[(long)(n0 + r) * DM + k0 + kq];
    As[kq + 0][r] = av.x; As[kq + 1][r] = av.y; As[kq + 2][r] = av.z; As[kq + 3][r] = av.w;
    Bs[kq + 0][r] = bv.x; Bs[kq + 1][r] = bv.y; Bs[kq + 2][r] = bv.z; Bs[kq + 3][r] = bv.w;
    __syncthreads();
#pragma unroll
    for (int k = 0; k < 8; k++) {
      float a[8], bb[8];
#pragma unroll
      for (int i = 0; i < 8; i++) a[i] = As[k][ty * 8 + i];
#pragma unroll
      for (int j = 0; j < 8; j++) bb[j] = Bs[k][tx * 8 + j];
#pragma unroll
      for (int i = 0; i < 8; i++)
#pragma unroll
        for (int j = 0; j < 8; j++) acc[i][j] += a[i] * bb[j];
    }
    __syncthreads();
  }

  float bj[8];
#pragma unroll
  for (int j = 0; j < 8; j++) bj[j] = bias[n0 + tx * 8 + j];
#pragma unroll
  for (int i = 0; i < 8; i++) {
    int gm = m0 + ty * 8 + i;
    if (gm >= M) continue;
    float* dst = &C[(long)gm * ldc + n0 + tx * 8];
    float4 o0 = make_float4(acc[i][0] + bj[0], acc[i][1] + bj[1],
                            acc[i][2] + bj[2], acc[i][3] + bj[3]);
    float4 o1 = make_float4(acc[i][4] + bj[4], acc[i][5] + bj[5],
                            acc[i][6] + bj[6], acc[i][7] + bj[7]);
    *(float4*)dst = o0;
    *(float4*)(dst + 4) = o1;
  }
}

// ---------------- attention: one block per (batch b, head h) ----------------
__global__ __launch_bounds__(256) void k_attn(const float* __restrict__ QKV,
                                              const float* __restrict__ bias,
                                              const int* __restrict__ starts,
                                              float* __restrict__ O) {
  __shared__ float Qs[128][32];
  __shared__ float Ks[128][33];  // +1 pad: per-lane row dots would be 64-way conflicted
  __shared__ float Vs[128][32];
  __shared__ float Ps[4][128];
  const int b = blockIdx.x, h = blockIdx.y;
  const int s0 = starts[b];
  const int cnt = starts[b + 1] - s0;
  const int tid = threadIdx.x;
  {
    const int r = tid >> 1, half = tid & 1;
    const bool valid = r < cnt;
    const float* base = QKV + (long)(s0 + r) * 1536 + h * 32 + half * 16;
    const float4 z = make_float4(0.f, 0.f, 0.f, 0.f);
    float4 q0 = valid ? *(const float4*)(base + 0) : z;
    float4 q1 = valid ? *(const float4*)(base + 4) : z;
    float4 q2 = valid ? *(const float4*)(base + 8) : z;
    float4 q3 = valid ? *(const float4*)(base + 12) : z;
    *(float4*)&Qs[r][half * 16 + 0] = q0;
    *(float4*)&Qs[r][half * 16 + 4] = q1;
    *(float4*)&Qs[r][half * 16 + 8] = q2;
    *(float4*)&Qs[r][half * 16 + 12] = q3;
    float4 k0 = valid ? *(const float4*)(base + 512 + 0) : z;
    float4 k1 = valid ? *(const float4*)(base + 512 + 4) : z;
    float4 k2 = valid ? *(const float4*)(base + 512 + 8) : z;
    float4 k3 = valid ? *(const float4*)(base + 512 + 12) : z;
    float kv[16] = {k0.x, k0.y, k0.z, k0.w, k1.x, k1.y, k1.z, k1.w,
                    k2.x, k2.y, k2.z, k2.w, k3.x, k3.y, k3.z, k3.w};
#pragma unroll
    for (int j = 0; j < 16; j++) Ks[r][half * 16 + j] = kv[j];
    float4 v0 = valid ? *(const float4*)(base + 1024 + 0) : z;
    float4 v1 = valid ? *(const float4*)(base + 1024 + 4) : z;
    float4 v2 = valid ? *(const float4*)(base + 1024 + 8) : z;
    float4 v3 = valid ? *(const float4*)(base + 1024 + 12) : z;
    *(float4*)&Vs[r][half * 16 + 0] = v0;
    *(float4*)&Vs[r][half * 16 + 4] = v1;
    *(float4*)&Vs[r][half * 16 + 8] = v2;
    *(float4*)&Vs[r][half * 16 + 12] = v3;
  }
  __syncthreads();
  const int lane = tid & 63, w = tid >> 6;
  const int d = lane & 31, hf = lane >> 5;
  for (int q = w; q < cnt; q += 4) {
    float sa = 0.f, sb = 0.f;
#pragma unroll
    for (int dd = 0; dd < 32; dd++) {
      float qd = Qs[q][dd];
      sa += qd * Ks[lane][dd];
      sb += qd * Ks[lane + 64][dd];
    }
    const float* brow = bias + (((long)(b * 16 + h) * 128) + q) * 128;
    sa = (lane < cnt) ? sa * SCALE_F + brow[lane] : -1e30f;
    sb = (lane + 64 < cnt) ? sb * SCALE_F + brow[lane + 64] : -1e30f;
    float mx = fmaxf(sa, sb);
#pragma unroll
    for (int off = 32; off > 0; off >>= 1) mx = fmaxf(mx, __shfl_xor(mx, off));
    float pa = expf(sa - mx), pb = expf(sb - mx);
    float sum = pa + pb;
#pragma unroll
    for (int off = 32; off > 0; off >>= 1) sum += __shfl_xor(sum, off);
    const float inv = 1.f / sum;
    Ps[w][lane] = pa * inv;
    Ps[w][lane + 64] = pb * inv;  // same-wave LDS RAW: in-order LDS pipe per wave
    float acc = 0.f;
#pragma unroll 8
    for (int kk = 0; kk < 64; kk++) {
      int k = hf * 64 + kk;
      acc += Ps[w][k] * Vs[k][d];
    }
    acc += __shfl_xor(acc, 32);
    if (lane < 32) O[(long)(s0 + q) * 512 + h * 32 + d] = acc;
  }
}

// ---------------- residual + LayerNorm, one wave per row ----------------
__global__ __launch_bounds__(256) void k_ln(const float* __restrict__ proj,
                                            const float* __restrict__ x,
                                            const float* __restrict__ lw,
                                            const float* __restrict__ lb,
                                            float* __restrict__ out) {
  const int row = blockIdx.x * 4 + (threadIdx.x >> 6);
  if (row >= NTOT) return;
  const int lane = threadIdx.x & 63;
  const float* pr = proj + (long)row * 512 + lane * 8;
  const float* xr = x + (long)row * 512 + lane * 8;
  float4 p0 = *(const float4*)pr;
  float4 p1 = *(const float4*)(pr + 4);
  float4 x0 = *(const float4*)xr;
  float4 x1 = *(const float4*)(xr + 4);
  float v[8] = {p0.x + x0.x, p0.y + x0.y, p0.z + x0.z, p0.w + x0.w,
                p1.x + x1.x, p1.y + x1.y, p1.z + x1.z, p1.w + x1.w};
  float s = 0.f, s2 = 0.f;
#pragma unroll
  for (int j = 0; j < 8; j++) { s += v[j]; s2 += v[j] * v[j]; }
#pragma unroll
  for (int off = 32; off > 0; off >>= 1) {
    s += __shfl_xor(s, off);
    s2 += __shfl_xor(s2, off);
  }
  const float mu = s * (1.f / 512.f);
  const float var = s2 * (1.f / 512.f) - mu * mu;
  const float inv = rsqrtf(var + 1e-5f);
  float4 w0 = *(const float4*)&lw[lane * 8];
  float4 w1 = *(const float4*)&lw[lane * 8 + 4];
  float4 b0 = *(const float4*)&lb[lane * 8];
  float4 b1 = *(const float4*)&lb[lane * 8 + 4];
  float4 o0 = make_float4((v[0] - mu) * inv * w0.x + b0.x, (v[1] - mu) * inv * w0.y + b0.y,
                          (v[2] - mu) * inv * w0.z + b0.z, (v[3] - mu) * inv * w0.w + b0.w);
  float4 o1 = make_float4((v[4] - mu) * inv * w1.x + b1.x, (v[5] - mu) * inv * w1.y + b1.y,
                          (v[6] - mu) * inv * w1.z + b1.z, (v[7] - mu) * inv * w1.w + b1.w);
  float* dst = out + (long)row * 512 + lane * 8;
  *(float4*)dst = o0;
  *(float4*)(dst + 4) = o1;
}

extern "C" void kernel_launch(void* const* d_in, const int* in_sizes, int n_in,
                              void* d_out, int out_size, void* d_ws, size_t ws_size,
                              hipStream_t stream) {
  const float* x = (const float*)d_in[0];
  const float* attn_bias = (const float*)d_in[1];
  const float* Wq = (const float*)d_in[2];
  const float* bq = (const float*)d_in[3];
  const float* Wk = (const float*)d_in[4];
  const float* bk = (const float*)d_in[5];
  const float* Wv = (const float*)d_in[6];
  const float* bv = (const float*)d_in[7];
  const float* Wp = (const float*)d_in[8];
  const float* bp = (const float*)d_in[9];
  const float* ln_w = (const float*)d_in[10];
  const float* ln_b = (const float*)d_in[11];
  const int* batch = (const int*)d_in[12];
  float* out = (float*)d_out;

  char* ws = (char*)d_ws;
  int* starts = (int*)ws;            // starts[0..64] = 260 bytes
  float* QKV = (float*)(ws + 512);   // FIX: was ws+256, aliased starts[64] with QKV[0]
  float* proj = QKV;                 // reused after attention

  k_starts<<<(NTOT + 255) / 256, 256, 0, stream>>>(batch, starts);

  dim3 g1((NTOT + 127) / 128, 4);
  k_gemm<<<g1, 256, 0, stream>>>(x, DM, Wq, bq, QKV + 0, 1536, NTOT);
  k_gemm<<<g1, 256, 0, stream>>>(x, DM, Wk, bk, QKV + 512, 1536, NTOT);
  k_gemm<<<g1, 256, 0, stream>>>(x, DM, Wv, bv, QKV + 1024, 1536, NTOT);

  dim3 g2(NB, 16);
  k_attn<<<g2, 256, 0, stream>>>(QKV, attn_bias, starts, out);  // out = attention O scratch

  k_gemm<<<g1, 256, 0, stream>>>(out, DM, Wp, bp, proj, DM, NTOT);

  k_ln<<<(NTOT + 3) / 4, 256, 0, stream>>>(proj, x, ln_w, ln_b, out);
}

// Round 4
// 161.054 us; speedup vs baseline: 2.7752x; 2.7752x over previous
//
#include <hip/hip_runtime.h>
#include <math.h>

#define NTOT 6148
#define NB 64
#define DM 512
#define SCALE_F 0.17677669529663687f

typedef __attribute__((ext_vector_type(8))) short bf16x8;
typedef __attribute__((ext_vector_type(4))) float f32x4;

__device__ __forceinline__ short f2bf(float f) {
  union { float f; unsigned u; } v; v.f = f;
  unsigned r = (v.u + 0x7fffu + ((v.u >> 16) & 1u)) >> 16;
  return (short)r;
}

__device__ __forceinline__ void gl_lds16(const short* g, void* l) {
  auto gp = (const __attribute__((address_space(1))) unsigned*)(unsigned long long)(g);
  auto lp = (__attribute__((address_space(3))) unsigned*)(unsigned long long)(
      (unsigned long long)__builtin_amdgcn_s_getpc() * 0 + (unsigned long long)(uintptr_t)l);
  __builtin_amdgcn_global_load_lds(gp, lp, 16, 0, 0);
}

// ---------------- starts from batch array ----------------
__global__ __launch_bounds__(256) void k_starts(const int* __restrict__ batch,
                                                int* __restrict__ starts) {
  int i = blockIdx.x * 256 + threadIdx.x;
  if (i >= NTOT) return;
  int b = batch[i];
  if (i == 0) starts[b] = 0;
  else if (batch[i - 1] != b) starts[b] = i;
  if (i == NTOT - 1) starts[NB] = NTOT;
}

// ---------------- f32 -> bf16 conversion (x + 4 weight matrices) ----------------
__global__ __launch_bounds__(256) void k_cvt(const float* __restrict__ x,
                                             const float* __restrict__ wq,
                                             const float* __restrict__ wk,
                                             const float* __restrict__ wv,
                                             const float* __restrict__ wp,
                                             short* __restrict__ xb,
                                             short* __restrict__ wqb,
                                             short* __restrict__ wkb,
                                             short* __restrict__ wvb,
                                             short* __restrict__ wpb) {
  const int bid = blockIdx.x;
  const float* s; short* d; long off;
  if (bid < 1537) {  // 1537*2048 == NTOT*512 exactly
    s = x; d = xb;
    off = ((long)bid * 256 + threadIdx.x) * 8;
  } else {
    int wi = (bid - 1537) >> 7;  // 128 blocks per 512x512 matrix
    s = (wi == 0) ? wq : (wi == 1) ? wk : (wi == 2) ? wv : wp;
    d = (wi == 0) ? wqb : (wi == 1) ? wkb : (wi == 2) ? wvb : wpb;
    off = ((long)((bid - 1537) & 127) * 256 + threadIdx.x) * 8;
  }
  float4 v0 = *(const float4*)(s + off);
  float4 v1 = *(const float4*)(s + off + 4);
  bf16x8 o;
  o[0] = f2bf(v0.x); o[1] = f2bf(v0.y); o[2] = f2bf(v0.z); o[3] = f2bf(v0.w);
  o[4] = f2bf(v1.x); o[5] = f2bf(v1.y); o[6] = f2bf(v1.z); o[7] = f2bf(v1.w);
  *(bf16x8*)(d + off) = o;
}

// ---------------- bf16 MFMA GEMM: C[M][ldc] = A[M][512](bf16) @ W[N][512](bf16)^T + bias ----
// 128x128 tile, BK=32, 4 waves (2x2 of 64x64), m97 structure (global_load_lds w16).
__global__ __launch_bounds__(256) void k_gemm_mfma(
    const short* __restrict__ Abf,
    const short* __restrict__ W0, const short* __restrict__ W1, const short* __restrict__ W2,
    const float* __restrict__ b0, const float* __restrict__ b1, const float* __restrict__ b2,
    const float* __restrict__ resid, float* __restrict__ C, int ldc, int M) {
  __shared__ __align__(16) short As[128][32];
  __shared__ __align__(16) short Bs[128][32];
  const int tid = threadIdx.x;
  const int w = tid >> 6, l = tid & 63;
  const int m0 = blockIdx.x * 128;
  const int n0 = blockIdx.y * 128;
  const int sel = n0 >> 9;
  const short* Wt = (sel == 0) ? W0 : (sel == 1) ? W1 : W2;
  const float* bt = (sel == 0) ? b0 : (sel == 1) ? b1 : b2;
  const int nl0 = n0 & 511;
  const int wr = w >> 1, wc = w & 1;
  const int lr = l >> 2;        // row within 16-row group (64B rows)
  const int lc = (l & 3) * 8;   // short offset of this lane's 16B chunk

  f32x4 acc[4][4];
#pragma unroll
  for (int m = 0; m < 4; m++)
#pragma unroll
    for (int n = 0; n < 4; n++) acc[m][n] = (f32x4){0.f, 0.f, 0.f, 0.f};

  for (int k0 = 0; k0 < 512; k0 += 32) {
    // stage: wave w fills rows [w*32, w*32+32) of As and Bs
    {
      const int r0 = w * 32 + lr, r1 = r0 + 16;
      gl_lds16(Abf + (long)min(m0 + r0, M - 1) * 512 + k0 + lc, &As[w * 32][0]);
      gl_lds16(Abf + (long)min(m0 + r1, M - 1) * 512 + k0 + lc, &As[w * 32 + 16][0]);
      gl_lds16(Wt + (long)(nl0 + r0) * 512 + k0 + lc, &Bs[w * 32][0]);
      gl_lds16(Wt + (long)(nl0 + r1) * 512 + k0 + lc, &Bs[w * 32 + 16][0]);
    }
    __syncthreads();
    const int fr = l & 15, fs = (l >> 4) * 8;
    bf16x8 af[4], bfr[4];
#pragma unroll
    for (int m = 0; m < 4; m++) af[m] = *(const bf16x8*)&As[wr * 64 + m * 16 + fr][fs];
#pragma unroll
    for (int n = 0; n < 4; n++) bfr[n] = *(const bf16x8*)&Bs[wc * 64 + n * 16 + fr][fs];
#pragma unroll
    for (int m = 0; m < 4; m++)
#pragma unroll
      for (int n = 0; n < 4; n++)
        acc[m][n] = __builtin_amdgcn_mfma_f32_16x16x32_bf16(af[m], bfr[n], acc[m][n], 0, 0, 0);
    __syncthreads();
  }

  // epilogue: C/D layout col=lane&15, row=(lane>>4)*4+j
  const int er = (l >> 4) * 4, ec = l & 15;
#pragma unroll
  for (int n = 0; n < 4; n++) {
    const int col = n0 + wc * 64 + n * 16 + ec;
    const float bv = bt[col & 511];
#pragma unroll
    for (int m = 0; m < 4; m++) {
      const int rowb = m0 + wr * 64 + m * 16 + er;
#pragma unroll
      for (int j = 0; j < 4; j++) {
        const int row = rowb + j;
        if (row < M) {
          float v = acc[m][n][j] + bv;
          if (resid) v += resid[(long)row * 512 + col];
          C[(long)row * ldc + col] = v;
        }
      }
    }
  }
}

// ---------------- attention: block = (head h, q-chunk qc, batch b) ----------------
__global__ __launch_bounds__(256) void k_attn(const float* __restrict__ QKV,
                                              const float* __restrict__ bias,
                                              const int* __restrict__ starts,
                                              short* __restrict__ Obf) {
  __shared__ __align__(16) float Qs[32][32];
  __shared__ __align__(16) float Ks[128][36];  // 144B rows: 16B-aligned, conflict-friendly
  __shared__ __align__(16) float Vs[128][32];
  __shared__ float Ps[4][128];
  const int h = blockIdx.x, qc = blockIdx.y, b = blockIdx.z;
  const int s0 = starts[b];
  const int cnt = starts[b + 1] - s0;
  const int q0 = qc * 32;
  if (q0 >= cnt) return;
  const int qend = min(cnt, q0 + 32);
  const int tid = threadIdx.x;
  {
    const int r = tid >> 1, half = tid & 1;
    const bool valid = r < cnt;
    const float* base = QKV + (long)(s0 + r) * 1536 + h * 32 + half * 16;
    const float4 z = make_float4(0.f, 0.f, 0.f, 0.f);
    float4 k0 = valid ? *(const float4*)(base + 512 + 0) : z;
    float4 k1 = valid ? *(const float4*)(base + 512 + 4) : z;
    float4 k2 = valid ? *(const float4*)(base + 512 + 8) : z;
    float4 k3 = valid ? *(const float4*)(base + 512 + 12) : z;
    *(float4*)&Ks[r][half * 16 + 0] = k0;
    *(float4*)&Ks[r][half * 16 + 4] = k1;
    *(float4*)&Ks[r][half * 16 + 8] = k2;
    *(float4*)&Ks[r][half * 16 + 12] = k3;
    float4 v0 = valid ? *(const float4*)(base + 1024 + 0) : z;
    float4 v1 = valid ? *(const float4*)(base + 1024 + 4) : z;
    float4 v2 = valid ? *(const float4*)(base + 1024 + 8) : z;
    float4 v3 = valid ? *(const float4*)(base + 1024 + 12) : z;
    *(float4*)&Vs[r][half * 16 + 0] = v0;
    *(float4*)&Vs[r][half * 16 + 4] = v1;
    *(float4*)&Vs[r][half * 16 + 8] = v2;
    *(float4*)&Vs[r][half * 16 + 12] = v3;
    if (tid < 64) {
      const int rq = q0 + (tid >> 1);
      const bool qv = rq < cnt;
      const float* qb = QKV + (long)(s0 + rq) * 1536 + h * 32 + half * 16;
      float4 q0v = qv ? *(const float4*)(qb + 0) : z;
      float4 q1v = qv ? *(const float4*)(qb + 4) : z;
      float4 q2v = qv ? *(const float4*)(qb + 8) : z;
      float4 q3v = qv ? *(const float4*)(qb + 12) : z;
      *(float4*)&Qs[tid >> 1][half * 16 + 0] = q0v;
      *(float4*)&Qs[tid >> 1][half * 16 + 4] = q1v;
      *(float4*)&Qs[tid >> 1][half * 16 + 8] = q2v;
      *(float4*)&Qs[tid >> 1][half * 16 + 12] = q3v;
    }
  }
  __syncthreads();
  const int lane = tid & 63, w = tid >> 6;
  // pull this lane's two K rows into registers (fully unrolled -> stays in VGPRs)
  float kr0[32], kr1[32];
#pragma unroll
  for (int j = 0; j < 8; j++) {
    *(float4*)&kr0[j * 4] = *(const float4*)&Ks[lane][j * 4];
    *(float4*)&kr1[j * 4] = *(const float4*)&Ks[lane + 64][j * 4];
  }
  const int d = lane & 31, hf = lane >> 5;
  const float* bbase = bias + ((long)(b * 16 + h) * 128) * 128;
  int q = q0 + w;
  float ba = 0.f, bb2 = 0.f;
  if (q < qend) { ba = bbase[q * 128 + lane]; bb2 = bbase[q * 128 + lane + 64]; }
  for (; q < qend; q += 4) {
    const int qn = q + 4;
    float nba = 0.f, nbb = 0.f;
    if (qn < qend) { nba = bbase[qn * 128 + lane]; nbb = bbase[qn * 128 + lane + 64]; }
    float sa = 0.f, sb = 0.f;
#pragma unroll
    for (int j = 0; j < 8; j++) {
      const float4 qv = *(const float4*)&Qs[q - q0][j * 4];  // LDS broadcast
      sa += qv.x * kr0[j * 4 + 0] + qv.y * kr0[j * 4 + 1] +
            qv.z * kr0[j * 4 + 2] + qv.w * kr0[j * 4 + 3];
      sb += qv.x * kr1[j * 4 + 0] + qv.y * kr1[j * 4 + 1] +
            qv.z * kr1[j * 4 + 2] + qv.w * kr1[j * 4 + 3];
    }
    sa = (lane < cnt) ? sa * SCALE_F + ba : -1e30f;
    sb = (lane + 64 < cnt) ? sb * SCALE_F + bb2 : -1e30f;
    float mx = fmaxf(sa, sb);
#pragma unroll
    for (int off = 32; off > 0; off >>= 1) mx = fmaxf(mx, __shfl_xor(mx, off));
    float pa = expf(sa - mx), pb = expf(sb - mx);
    float sum = pa + pb;
#pragma unroll
    for (int off = 32; off > 0; off >>= 1) sum += __shfl_xor(sum, off);
    const float inv = 1.f / sum;
    Ps[w][lane] = pa * inv;
    Ps[w][lane + 64] = pb * inv;  // same-wave LDS RAW: in-order per-wave LDS pipe
    float acc = 0.f;
#pragma unroll 8
    for (int kk = 0; kk < 64; kk++) {
      const int k = hf * 64 + kk;
      acc += Ps[w][k] * Vs[k][d];
    }
    acc += __shfl_xor(acc, 32);
    if (lane < 32) Obf[(long)(s0 + q) * 512 + h * 32 + d] = f2bf(acc);
    ba = nba; bb2 = nbb;
  }
}

// ---------------- LayerNorm (residual pre-added), one wave per row ----------------
__global__ __launch_bounds__(256) void k_lnp(const float* __restrict__ pre,
                                             const float* __restrict__ lw,
                                             const float* __restrict__ lb,
                                             float* __restrict__ out) {
  const int row = blockIdx.x * 4 + (threadIdx.x >> 6);
  if (row >= NTOT) return;
  const int lane = threadIdx.x & 63;
  const float* pr = pre + (long)row * 512 + lane * 8;
  float4 p0 = *(const float4*)pr;
  float4 p1 = *(const float4*)(pr + 4);
  float v[8] = {p0.x, p0.y, p0.z, p0.w, p1.x, p1.y, p1.z, p1.w};
  float s = 0.f, s2 = 0.f;
#pragma unroll
  for (int j = 0; j < 8; j++) { s += v[j]; s2 += v[j] * v[j]; }
#pragma unroll
  for (int off = 32; off > 0; off >>= 1) {
    s += __shfl_xor(s, off);
    s2 += __shfl_xor(s2, off);
  }
  const float mu = s * (1.f / 512.f);
  const float var = s2 * (1.f / 512.f) - mu * mu;
  const float inv = rsqrtf(var + 1e-5f);
  float4 w0 = *(const float4*)&lw[lane * 8];
  float4 w1 = *(const float4*)&lw[lane * 8 + 4];
  float4 b0 = *(const float4*)&lb[lane * 8];
  float4 b1 = *(const float4*)&lb[lane * 8 + 4];
  float4 o0 = make_float4((v[0] - mu) * inv * w0.x + b0.x, (v[1] - mu) * inv * w0.y + b0.y,
                          (v[2] - mu) * inv * w0.z + b0.z, (v[3] - mu) * inv * w0.w + b0.w);
  float4 o1 = make_float4((v[4] - mu) * inv * w1.x + b1.x, (v[5] - mu) * inv * w1.y + b1.y,
                          (v[6] - mu) * inv * w1.z + b1.z, (v[7] - mu) * inv * w1.w + b1.w);
  float* dst = out + (long)row * 512 + lane * 8;
  *(float4*)dst = o0;
  *(float4*)(dst + 4) = o1;
}

extern "C" void kernel_launch(void* const* d_in, const int* in_sizes, int n_in,
                              void* d_out, int out_size, void* d_ws, size_t ws_size,
                              hipStream_t stream) {
  const float* x = (const float*)d_in[0];
  const float* attn_bias = (const float*)d_in[1];
  const float* Wq = (const float*)d_in[2];
  const float* bq = (const float*)d_in[3];
  const float* Wk = (const float*)d_in[4];
  const float* bk = (const float*)d_in[5];
  const float* Wv = (const float*)d_in[6];
  const float* bv = (const float*)d_in[7];
  const float* Wp = (const float*)d_in[8];
  const float* bp = (const float*)d_in[9];
  const float* ln_w = (const float*)d_in[10];
  const float* ln_b = (const float*)d_in[11];
  const int* batch = (const int*)d_in[12];
  float* out = (float*)d_out;

  char* ws = (char*)d_ws;
  int* starts = (int*)ws;                       // 65 ints (512B reserved)
  short* Xbf = (short*)(ws + 512);              // NTOT x 512 bf16
  short* Wqb = Xbf + (long)NTOT * 512;
  short* Wkb = Wqb + 512 * 512;
  short* Wvb = Wkb + 512 * 512;
  short* Wpb = Wvb + 512 * 512;
  float* QKV = (float*)(Wpb + 512 * 512);       // NTOT x 1536 f32
  short* Obf = Xbf;                             // reuse: Xbf dead after QKV GEMM
  float* proj = QKV;                            // reuse: QKV dead after attention

  k_starts<<<(NTOT + 255) / 256, 256, 0, stream>>>(batch, starts);
  k_cvt<<<1537 + 4 * 128, 256, 0, stream>>>(x, Wq, Wk, Wv, Wp, Xbf, Wqb, Wkb, Wvb, Wpb);

  dim3 gq((NTOT + 127) / 128, 12);  // fused QKV: N = 1536
  k_gemm_mfma<<<gq, 256, 0, stream>>>(Xbf, Wqb, Wkb, Wvb, bq, bk, bv,
                                      nullptr, QKV, 1536, NTOT);

  dim3 ga(16, 4, NB);  // h fastest for K/V L2 reuse
  k_attn<<<ga, 256, 0, stream>>>(QKV, attn_bias, starts, Obf);

  dim3 gp((NTOT + 127) / 128, 4);  // proj: N = 512, residual fused
  k_gemm_mfma<<<gp, 256, 0, stream>>>(Obf, Wpb, Wpb, Wpb, bp, bp, bp,
                                      x, proj, 512, NTOT);

  k_lnp<<<(NTOT + 3) / 4, 256, 0, stream>>>(proj, ln_w, ln_b, out);
}

// Round 5
// 104.171 us; speedup vs baseline: 4.2906x; 1.5461x over previous
//
#include <hip/hip_runtime.h>
#include <math.h>

#define NTOT 6148
#define NB 64
#define DM 512
#define SCALE_F 0.17677669529663687f

typedef __attribute__((ext_vector_type(8))) short bf16x8;
typedef __attribute__((ext_vector_type(4))) float f32x4;

__device__ __forceinline__ short f2bf(float f) {
  union { float f; unsigned u; } v; v.f = f;
  unsigned r = (v.u + 0x7fffu + ((v.u >> 16) & 1u)) >> 16;
  return (short)r;
}

__device__ __forceinline__ void gl_lds16(const short* g, void* l) {
  auto gp = (const __attribute__((address_space(1))) unsigned*)(unsigned long long)(g);
  auto lp = (__attribute__((address_space(3))) unsigned*)(unsigned long long)(uintptr_t)l;
  __builtin_amdgcn_global_load_lds(gp, lp, 16, 0, 0);
}

// ---------------- starts from batch array ----------------
__global__ __launch_bounds__(256) void k_starts(const int* __restrict__ batch,
                                                int* __restrict__ starts) {
  int i = blockIdx.x * 256 + threadIdx.x;
  if (i >= NTOT) return;
  int b = batch[i];
  if (i == 0) starts[b] = 0;
  else if (batch[i - 1] != b) starts[b] = i;
  if (i == NTOT - 1) starts[NB] = NTOT;
}

// ---------------- f32 -> bf16 conversion (x + 4 weight matrices) ----------------
__global__ __launch_bounds__(256) void k_cvt(const float* __restrict__ x,
                                             const float* __restrict__ wq,
                                             const float* __restrict__ wk,
                                             const float* __restrict__ wv,
                                             const float* __restrict__ wp,
                                             short* __restrict__ xb,
                                             short* __restrict__ wqb,
                                             short* __restrict__ wkb,
                                             short* __restrict__ wvb,
                                             short* __restrict__ wpb) {
  const int bid = blockIdx.x;
  const float* s; short* d; long off;
  if (bid < 1537) {  // 1537*2048 == NTOT*512 exactly
    s = x; d = xb;
    off = ((long)bid * 256 + threadIdx.x) * 8;
  } else {
    int wi = (bid - 1537) >> 7;  // 128 blocks per 512x512 matrix
    s = (wi == 0) ? wq : (wi == 1) ? wk : (wi == 2) ? wv : wp;
    d = (wi == 0) ? wqb : (wi == 1) ? wkb : (wi == 2) ? wvb : wpb;
    off = ((long)((bid - 1537) & 127) * 256 + threadIdx.x) * 8;
  }
  float4 v0 = *(const float4*)(s + off);
  float4 v1 = *(const float4*)(s + off + 4);
  bf16x8 o;
  o[0] = f2bf(v0.x); o[1] = f2bf(v0.y); o[2] = f2bf(v0.z); o[3] = f2bf(v0.w);
  o[4] = f2bf(v1.x); o[5] = f2bf(v1.y); o[6] = f2bf(v1.z); o[7] = f2bf(v1.w);
  *(bf16x8*)(d + off) = o;
}

// ---------------- bf16 MFMA GEMM: C = A[M][512](bf16) @ W[N][512](bf16)^T + bias ----
// 128x128 tile, BK=32, 4 waves (2x2 of 64x64). BF16OUT selects output dtype.
template <bool BF16OUT>
__global__ __launch_bounds__(256) void k_gemm_mfma(
    const short* __restrict__ Abf,
    const short* __restrict__ W0, const short* __restrict__ W1, const short* __restrict__ W2,
    const float* __restrict__ b0, const float* __restrict__ b1, const float* __restrict__ b2,
    const float* __restrict__ resid, void* __restrict__ Cv, int ldc, int M) {
  __shared__ __align__(16) short As[128][32];
  __shared__ __align__(16) short Bs[128][32];
  const int tid = threadIdx.x;
  const int w = tid >> 6, l = tid & 63;
  const int m0 = blockIdx.x * 128;
  const int n0 = blockIdx.y * 128;
  const int sel = n0 >> 9;
  const short* Wt = (sel == 0) ? W0 : (sel == 1) ? W1 : W2;
  const float* bt = (sel == 0) ? b0 : (sel == 1) ? b1 : b2;
  const int nl0 = n0 & 511;
  const int wr = w >> 1, wc = w & 1;
  const int lr = l >> 2;        // row within 16-row group (64B rows)
  const int lc = (l & 3) * 8;   // short offset of this lane's 16B chunk

  f32x4 acc[4][4];
#pragma unroll
  for (int m = 0; m < 4; m++)
#pragma unroll
    for (int n = 0; n < 4; n++) acc[m][n] = (f32x4){0.f, 0.f, 0.f, 0.f};

  for (int k0 = 0; k0 < 512; k0 += 32) {
    {
      const int r0 = w * 32 + lr, r1 = r0 + 16;
      gl_lds16(Abf + (long)min(m0 + r0, M - 1) * 512 + k0 + lc, &As[w * 32][0]);
      gl_lds16(Abf + (long)min(m0 + r1, M - 1) * 512 + k0 + lc, &As[w * 32 + 16][0]);
      gl_lds16(Wt + (long)(nl0 + r0) * 512 + k0 + lc, &Bs[w * 32][0]);
      gl_lds16(Wt + (long)(nl0 + r1) * 512 + k0 + lc, &Bs[w * 32 + 16][0]);
    }
    __syncthreads();
    const int fr = l & 15, fs = (l >> 4) * 8;
    bf16x8 af[4], bfr[4];
#pragma unroll
    for (int m = 0; m < 4; m++) af[m] = *(const bf16x8*)&As[wr * 64 + m * 16 + fr][fs];
#pragma unroll
    for (int n = 0; n < 4; n++) bfr[n] = *(const bf16x8*)&Bs[wc * 64 + n * 16 + fr][fs];
#pragma unroll
    for (int m = 0; m < 4; m++)
#pragma unroll
      for (int n = 0; n < 4; n++)
        acc[m][n] = __builtin_amdgcn_mfma_f32_16x16x32_bf16(af[m], bfr[n], acc[m][n], 0, 0, 0);
    __syncthreads();
  }

  // epilogue: C/D layout col=lane&15, row=(lane>>4)*4+j
  const int er = (l >> 4) * 4, ec = l & 15;
#pragma unroll
  for (int n = 0; n < 4; n++) {
    const int col = n0 + wc * 64 + n * 16 + ec;
    const float bv = bt[col & 511];
#pragma unroll
    for (int m = 0; m < 4; m++) {
      const int rowb = m0 + wr * 64 + m * 16 + er;
#pragma unroll
      for (int j = 0; j < 4; j++) {
        const int row = rowb + j;
        if (row < M) {
          float v = acc[m][n][j] + bv;
          if (resid) v += resid[(long)row * 512 + col];
          if (BF16OUT) ((short*)Cv)[(long)row * ldc + col] = f2bf(v);
          else ((float*)Cv)[(long)row * ldc + col] = v;
        }
      }
    }
  }
}

// ---------------- MFMA attention: one block per (h, b), 4 waves x 32 q-rows ----
__global__ __launch_bounds__(256) void k_attn(const short* __restrict__ QKVbf,
                                              const float* __restrict__ bias,
                                              const int* __restrict__ starts,
                                              short* __restrict__ Obf) {
  __shared__ __align__(16) short Qb[128][40];   // +8 pad: 20-dword rows spread banks
  __shared__ __align__(16) short Kb[128][40];
  __shared__ __align__(16) short Vtb[32][136];  // V transposed (rows = d), 68-dword rows
  __shared__ __align__(16) short Ps[128][136];  // P (per-wave 32-row strips)
  const int h = blockIdx.x, b = blockIdx.y;
  const int s0 = starts[b], cnt = starts[b + 1] - s0;
  const int tid = threadIdx.x;
  // ---- stage Q, K, V^T (bf16 in, zero-pad rows >= cnt) ----
  {
    const int r0 = tid >> 2;          // 0..63
    const int c = (tid & 3) * 8;      // 0,8,16,24 shorts
    const bf16x8 zz = {0, 0, 0, 0, 0, 0, 0, 0};
#pragma unroll
    for (int rr = r0; rr < 128; rr += 64) {
      const bool valid = rr < cnt;
      const short* rowp = QKVbf + (long)(s0 + (valid ? rr : 0)) * 1536 + h * 32 + c;
      bf16x8 qv = valid ? *(const bf16x8*)rowp : zz;
      bf16x8 kv = valid ? *(const bf16x8*)(rowp + 512) : zz;
      bf16x8 vv = valid ? *(const bf16x8*)(rowp + 1024) : zz;
      *(bf16x8*)&Qb[rr][c] = qv;
      *(bf16x8*)&Kb[rr][c] = kv;
#pragma unroll
      for (int i = 0; i < 8; i++) Vtb[c + i][rr] = vv[i];
    }
  }
  __syncthreads();
  const int l = tid & 63, w = tid >> 6;
  const int wq0 = w * 32;
  if (wq0 >= cnt) return;            // no barriers after this point
  const int lg = l >> 4, lk = l & 15, fs = lg * 8;
  const float* bbase = bias + ((long)(b * 16 + h) << 14);

  // ---- S = Q K^T (16 MFMA) ----
  f32x4 S[2][8];
  bf16x8 aq[2];
#pragma unroll
  for (int m = 0; m < 2; m++) aq[m] = *(const bf16x8*)&Qb[wq0 + m * 16 + lk][fs];
#pragma unroll
  for (int n = 0; n < 8; n++) {
    const bf16x8 bk8 = *(const bf16x8*)&Kb[n * 16 + lk][fs];
#pragma unroll
    for (int m = 0; m < 2; m++)
      S[m][n] = __builtin_amdgcn_mfma_f32_16x16x32_bf16(aq[m], bk8,
                                                        (f32x4){0.f, 0.f, 0.f, 0.f}, 0, 0, 0);
  }

  // ---- bias + scale + mask + softmax (16-lane row reduce), P -> LDS bf16 ----
#pragma unroll
  for (int m = 0; m < 2; m++) {
    const int qb0 = wq0 + m * 16 + lg * 4;
#pragma unroll
    for (int n = 0; n < 8; n++) {
      const int k = n * 16 + lk;
      const bool kok = k < cnt;
      const float* bp_ = bbase + (long)qb0 * 128 + k;
#pragma unroll
      for (int j = 0; j < 4; j++) {
        const float sv = S[m][n][j] * SCALE_F + bp_[j * 128];
        S[m][n][j] = kok ? sv : -1e30f;
      }
    }
#pragma unroll
    for (int j = 0; j < 4; j++) {
      float mx = S[m][0][j];
#pragma unroll
      for (int n = 1; n < 8; n++) mx = fmaxf(mx, S[m][n][j]);
      mx = fmaxf(mx, __shfl_xor(mx, 1));
      mx = fmaxf(mx, __shfl_xor(mx, 2));
      mx = fmaxf(mx, __shfl_xor(mx, 4));
      mx = fmaxf(mx, __shfl_xor(mx, 8));
      float sum = 0.f;
#pragma unroll
      for (int n = 0; n < 8; n++) {
        const float p = expf(S[m][n][j] - mx);
        S[m][n][j] = p;
        sum += p;
      }
      sum += __shfl_xor(sum, 1);
      sum += __shfl_xor(sum, 2);
      sum += __shfl_xor(sum, 4);
      sum += __shfl_xor(sum, 8);
      const float inv = 1.f / sum;
      const int qloc = qb0 + j;
#pragma unroll
      for (int n = 0; n < 8; n++) Ps[qloc][n * 16 + lk] = f2bf(S[m][n][j] * inv);
    }
  }

  // ---- O = P V (16 MFMA), same-wave LDS RAW ----
  f32x4 O[2][2];
#pragma unroll
  for (int m = 0; m < 2; m++)
#pragma unroll
    for (int dt = 0; dt < 2; dt++) O[m][dt] = (f32x4){0.f, 0.f, 0.f, 0.f};
#pragma unroll
  for (int kc = 0; kc < 4; kc++) {
    bf16x8 pa[2], vb[2];
#pragma unroll
    for (int m = 0; m < 2; m++) pa[m] = *(const bf16x8*)&Ps[wq0 + m * 16 + lk][kc * 32 + fs];
#pragma unroll
    for (int dt = 0; dt < 2; dt++) vb[dt] = *(const bf16x8*)&Vtb[dt * 16 + lk][kc * 32 + fs];
#pragma unroll
    for (int m = 0; m < 2; m++)
#pragma unroll
      for (int dt = 0; dt < 2; dt++)
        O[m][dt] = __builtin_amdgcn_mfma_f32_16x16x32_bf16(pa[m], vb[dt], O[m][dt], 0, 0, 0);
  }
  // ---- store O (bf16) ----
#pragma unroll
  for (int m = 0; m < 2; m++) {
    const int qb0 = wq0 + m * 16 + lg * 4;
#pragma unroll
    for (int j = 0; j < 4; j++) {
      if (qb0 + j < cnt) {
        short* orow = Obf + (long)(s0 + qb0 + j) * 512 + h * 32;
#pragma unroll
        for (int dt = 0; dt < 2; dt++) orow[dt * 16 + lk] = f2bf(O[m][dt][j]);
      }
    }
  }
}

// ---------------- LayerNorm (residual pre-added), one wave per row ----------------
__global__ __launch_bounds__(256) void k_lnp(const float* __restrict__ pre,
                                             const float* __restrict__ lw,
                                             const float* __restrict__ lb,
                                             float* __restrict__ out) {
  const int row = blockIdx.x * 4 + (threadIdx.x >> 6);
  if (row >= NTOT) return;
  const int lane = threadIdx.x & 63;
  const float* pr = pre + (long)row * 512 + lane * 8;
  float4 p0 = *(const float4*)pr;
  float4 p1 = *(const float4*)(pr + 4);
  float v[8] = {p0.x, p0.y, p0.z, p0.w, p1.x, p1.y, p1.z, p1.w};
  float s = 0.f, s2 = 0.f;
#pragma unroll
  for (int j = 0; j < 8; j++) { s += v[j]; s2 += v[j] * v[j]; }
#pragma unroll
  for (int off = 32; off > 0; off >>= 1) {
    s += __shfl_xor(s, off);
    s2 += __shfl_xor(s2, off);
  }
  const float mu = s * (1.f / 512.f);
  const float var = s2 * (1.f / 512.f) - mu * mu;
  const float inv = rsqrtf(var + 1e-5f);
  float4 w0 = *(const float4*)&lw[lane * 8];
  float4 w1 = *(const float4*)&lw[lane * 8 + 4];
  float4 b0 = *(const float4*)&lb[lane * 8];
  float4 b1 = *(const float4*)&lb[lane * 8 + 4];
  float4 o0 = make_float4((v[0] - mu) * inv * w0.x + b0.x, (v[1] - mu) * inv * w0.y + b0.y,
                          (v[2] - mu) * inv * w0.z + b0.z, (v[3] - mu) * inv * w0.w + b0.w);
  float4 o1 = make_float4((v[4] - mu) * inv * w1.x + b1.x, (v[5] - mu) * inv * w1.y + b1.y,
                          (v[6] - mu) * inv * w1.z + b1.z, (v[7] - mu) * inv * w1.w + b1.w);
  float* dst = out + (long)row * 512 + lane * 8;
  *(float4*)dst = o0;
  *(float4*)(dst + 4) = o1;
}

extern "C" void kernel_launch(void* const* d_in, const int* in_sizes, int n_in,
                              void* d_out, int out_size, void* d_ws, size_t ws_size,
                              hipStream_t stream) {
  const float* x = (const float*)d_in[0];
  const float* attn_bias = (const float*)d_in[1];
  const float* Wq = (const float*)d_in[2];
  const float* bq = (const float*)d_in[3];
  const float* Wk = (const float*)d_in[4];
  const float* bk = (const float*)d_in[5];
  const float* Wv = (const float*)d_in[6];
  const float* bv = (const float*)d_in[7];
  const float* Wp = (const float*)d_in[8];
  const float* bp = (const float*)d_in[9];
  const float* ln_w = (const float*)d_in[10];
  const float* ln_b = (const float*)d_in[11];
  const int* batch = (const int*)d_in[12];
  float* out = (float*)d_out;

  char* ws = (char*)d_ws;
  int* starts = (int*)ws;                        // 65 ints (512B reserved)
  short* Xbf = (short*)(ws + 512);               // NTOT x 512 bf16
  short* Wqb = Xbf + (long)NTOT * 512;
  short* Wkb = Wqb + 512 * 512;
  short* Wvb = Wkb + 512 * 512;
  short* Wpb = Wvb + 512 * 512;
  short* QKVbf = Wpb + 512 * 512;                // NTOT x 1536 bf16
  short* Obf = Xbf;                              // reuse: Xbf dead after QKV GEMM
  float* proj = (float*)QKVbf;                   // reuse: QKVbf dead after attention

  k_starts<<<(NTOT + 255) / 256, 256, 0, stream>>>(batch, starts);
  k_cvt<<<1537 + 4 * 128, 256, 0, stream>>>(x, Wq, Wk, Wv, Wp, Xbf, Wqb, Wkb, Wvb, Wpb);

  dim3 gq((NTOT + 127) / 128, 12);  // fused QKV: N = 1536, bf16 out
  k_gemm_mfma<true><<<gq, 256, 0, stream>>>(Xbf, Wqb, Wkb, Wvb, bq, bk, bv,
                                            nullptr, QKVbf, 1536, NTOT);

  dim3 ga(16, NB);  // (h, b)
  k_attn<<<ga, 256, 0, stream>>>(QKVbf, attn_bias, starts, Obf);

  dim3 gp((NTOT + 127) / 128, 4);  // proj: N = 512, residual fused, f32 out
  k_gemm_mfma<false><<<gp, 256, 0, stream>>>(Obf, Wpb, Wpb, Wpb, bp, bp, bp,
                                             x, proj, 512, NTOT);

  k_lnp<<<(NTOT + 3) / 4, 256, 0, stream>>>(proj, ln_w, ln_b, out);
}